// Round 4
// baseline (7244.781 us; speedup 1.0000x reference)
//
#include <hip/hip_runtime.h>

// Problem constants (B,S,D,H = 64,512,1024,1024)
#define S_LEN 512
#define BATCH 64
#define HDIM  1024
#define GDIM  3072   // 3*H

typedef __attribute__((ext_vector_type(8))) short bf16x8;           // MFMA A/B frag (8 bf16)
typedef __attribute__((ext_vector_type(4))) float f32x4;            // MFMA C/D frag
typedef __attribute__((ext_vector_type(4))) unsigned short u16x4;   // 4 bf16

__device__ inline unsigned short f2bf(float f) {
  unsigned u = __builtin_bit_cast(unsigned, f);
  u += 0x7fffu + ((u >> 16) & 1u);          // RNE (inputs are normal floats)
  return (unsigned short)(u >> 16);
}
__device__ inline float bf2f(unsigned short h) {
  unsigned u = ((unsigned)h) << 16;
  return __builtin_bit_cast(float, u);
}
__device__ inline bf16x8 pack8(float4 a, float4 b) {
  bf16x8 r;
  r[0] = (short)f2bf(a.x); r[1] = (short)f2bf(a.y);
  r[2] = (short)f2bf(a.z); r[3] = (short)f2bf(a.w);
  r[4] = (short)f2bf(b.x); r[5] = (short)f2bf(b.y);
  r[6] = (short)f2bf(b.z); r[7] = (short)f2bf(b.w);
  return r;
}

// MALL-direct 16B h-fragment load as 2x8B agent-scope relaxed atomics
// (sc0 sc1: bypass L1/L2, read the device coherence point -> no acquire-inv
// needed anywhere).
__device__ inline bf16x8 load_h8(const unsigned short* p) {
  unsigned long long a =
      __hip_atomic_load((const unsigned long long*)p, __ATOMIC_RELAXED, __HIP_MEMORY_SCOPE_AGENT);
  unsigned long long b =
      __hip_atomic_load((const unsigned long long*)(p + 4), __ATOMIC_RELAXED, __HIP_MEMORY_SCOPE_AGENT);
  union { unsigned long long u[2]; bf16x8 v; } c;
  c.u[0] = a; c.u[1] = b;
  return c.v;
}

// ---------------------------------------------------------------------------
// Phase 1: xg[s][g][b] = sum_d U[b][s][d] * Wih[g][d] + bih[g]   (bf16 out)
// (unchanged this round)
// ---------------------------------------------------------------------------
__global__ __launch_bounds__(256, 2) void xg_gemm(
    const float* __restrict__ U, const float* __restrict__ Wih,
    const float* __restrict__ bih, unsigned short* __restrict__ xg) {
  __shared__ bf16x8 Asub[512];   // 128 rows x 4 chunks (8KB)
  __shared__ bf16x8 Bsub[512];

  const int bid = blockIdx.x;
  const int nt = bid % 24;       // N-tile (gate cols) fastest: W_ih L2 reuse
  const int mt = bid / 24;
  const int tid = threadIdx.x;
  const int wave = tid >> 6, lane = tid & 63;
  const int q = lane >> 4, l15 = lane & 15;
  const int wm = wave >> 1, wn = wave & 1;

  const int srow = tid >> 1, shalf = tid & 1;
  const int arow = mt * 128 + srow;            // M index = s*64+b ordering
  const float* Ag = U + ((size_t)(arow & 63) * S_LEN + (arow >> 6)) * HDIM + shalf * 16;
  const float* Bg = Wih + (size_t)(nt * 128 + srow) * HDIM + shalf * 16;
  const int sw = (srow >> 1) & 3;
  const int slot0 = srow * 4 + ((shalf * 2) ^ sw);
  const int slot1 = srow * 4 + ((shalf * 2 + 1) ^ sw);

  f32x4 acc[4][4];
#pragma unroll
  for (int i = 0; i < 4; ++i)
#pragma unroll
    for (int j = 0; j < 4; ++j) acc[i][j] = (f32x4){0.f, 0.f, 0.f, 0.f};

  for (int kk = 0; kk < 32; ++kk) {
    const float4* ap = (const float4*)(Ag + kk * 32);
    float4 a0 = ap[0], a1 = ap[1], a2 = ap[2], a3 = ap[3];
    const float4* bp = (const float4*)(Bg + kk * 32);
    float4 b0 = bp[0], b1 = bp[1], b2 = bp[2], b3 = bp[3];
    Asub[slot0] = pack8(a0, a1);
    Asub[slot1] = pack8(a2, a3);
    Bsub[slot0] = pack8(b0, b1);
    Bsub[slot1] = pack8(b2, b3);
    __syncthreads();
    bf16x8 af[4], bfr[4];
#pragma unroll
    for (int i = 0; i < 4; ++i) {
      int ar = wm * 64 + i * 16 + l15;
      af[i] = Asub[ar * 4 + (q ^ ((ar >> 1) & 3))];
      int br = wn * 64 + i * 16 + l15;
      bfr[i] = Bsub[br * 4 + (q ^ ((br >> 1) & 3))];
    }
#pragma unroll
    for (int i = 0; i < 4; ++i)
#pragma unroll
      for (int j = 0; j < 4; ++j)
        acc[i][j] = __builtin_amdgcn_mfma_f32_16x16x32_bf16(af[i], bfr[j], acc[i][j], 0, 0, 0);
    __syncthreads();
  }

#pragma unroll
  for (int j = 0; j < 4; ++j) {
    int gcol = nt * 128 + wn * 64 + j * 16 + l15;
    float bias = bih[gcol];
#pragma unroll
    for (int i = 0; i < 4; ++i) {
      int rbase = mt * 128 + wm * 64 + i * 16 + q * 4;
      int s = rbase >> 6;
      int b0i = rbase & 63;
      u16x4 pk;
#pragma unroll
      for (int r = 0; r < 4; ++r) pk[r] = f2bf(acc[i][j][r] + bias);
      *(u16x4*)(xg + ((size_t)s * GDIM + gcol) * BATCH + b0i) = pk;
    }
  }
}

// ---------------------------------------------------------------------------
// Phase 2 (round-4): persistent GRU scan, 64 blocks x 256 threads.
// Block p owns h-cols [16p,16p+16); wave w owns k in [256w,256w+256) and
// computes partial pre-activations for all 3 gates (W_hh frags in VGPRs).
//
// Round-4 changes (round-3 was ~9us/step of sync/visibility cost):
//  * ALL cross-block h traffic is MALL-direct (agent relaxed atomics, sc0 sc1
//    bypass L1/L2). L2 never holds h: release-wbl2 sweeps a clean cache,
//    acquire-inv DELETED (nothing stale to invalidate).
//  * xg prefetch for t+1 issued between flag-add and poll -> HBM latency
//    hides under the barrier wait.
//  * part padded [16][66] (2-way banks = free, was 4-way); hstage + one
//    __syncthreads eliminated (thread owns 4 consecutive m -> own 8B store).
// ---------------------------------------------------------------------------
__global__ __launch_bounds__(256, 1) void gru_scan(
    const float* __restrict__ Whh, const float* __restrict__ bhh,
    const unsigned short* __restrict__ xg, unsigned short* __restrict__ hbuf,
    unsigned int* __restrict__ bar, float* __restrict__ out) {
  __shared__ float part[4][3][16][66];       // ~50.7 KB per-wave partial gates
  __shared__ float hown[64][16];             // fp32 carry [b][m]
  __shared__ float bh_lds[3][16];

  const int p = blockIdx.x;
  const int j0 = p * 16;
  const int tid = threadIdx.x;
  const int w = tid >> 6, lane = tid & 63;
  const int q = lane >> 4, l15 = lane & 15;
  const int k0 = w * 256;
  const int cb = tid >> 2;            // combine: batch row 0..63
  const int cmq = (tid & 3) * 4;      // combine: m-quad 0,4,8,12

  // A-frags: wf[g][kk] = Whh[g*1024 + j0 + l15][k0 + kk*32 + q*8 .. +7]
  bf16x8 wf[3][8];
#pragma unroll
  for (int g = 0; g < 3; ++g) {
    const float* wrow = Whh + ((size_t)g * HDIM + j0 + l15) * HDIM + k0;
#pragma unroll
    for (int kk = 0; kk < 8; ++kk) {
      const float4* wp = (const float4*)(wrow + kk * 32 + q * 8);
      wf[g][kk] = pack8(wp[0], wp[1]);
    }
  }
  if (tid < 48) bh_lds[tid >> 4][tid & 15] = bhh[(tid >> 4) * HDIM + j0 + (tid & 15)];
  { float4 z = {0.f, 0.f, 0.f, 0.f}; *(float4*)&hown[cb][cmq] = z; }
  __syncthreads();

  // prefetch xg for t=0
  unsigned short xq[3][4];
#pragma unroll
  for (int g = 0; g < 3; ++g)
#pragma unroll
    for (int r = 0; r < 4; ++r)
      xq[g][r] = xg[((size_t)g * HDIM + j0 + cmq + r) * BATCH + cb];

  for (int t = 0; t < S_LEN; ++t) {
    const unsigned short* hcur = hbuf + (size_t)(t & 1) * (BATCH * HDIM);
    unsigned short* hnxt = hbuf + (size_t)((t + 1) & 1) * (BATCH * HDIM);

    // ---- GEMM phase: hgT partials, h read MALL-direct ----
    f32x4 acc[3][4];
#pragma unroll
    for (int g = 0; g < 3; ++g)
#pragma unroll
      for (int bt = 0; bt < 4; ++bt) acc[g][bt] = (f32x4){0.f, 0.f, 0.f, 0.f};

    const unsigned short* hb = hcur + k0 + q * 8;
#pragma unroll
    for (int kk = 0; kk < 8; ++kk) {
      bf16x8 h0 = load_h8(hb + (size_t)(l15) * HDIM + kk * 32);
      bf16x8 h1 = load_h8(hb + (size_t)(16 + l15) * HDIM + kk * 32);
      bf16x8 h2 = load_h8(hb + (size_t)(32 + l15) * HDIM + kk * 32);
      bf16x8 h3 = load_h8(hb + (size_t)(48 + l15) * HDIM + kk * 32);
#pragma unroll
      for (int g = 0; g < 3; ++g) {
        acc[g][0] = __builtin_amdgcn_mfma_f32_16x16x32_bf16(wf[g][kk], h0, acc[g][0], 0, 0, 0);
        acc[g][1] = __builtin_amdgcn_mfma_f32_16x16x32_bf16(wf[g][kk], h1, acc[g][1], 0, 0, 0);
        acc[g][2] = __builtin_amdgcn_mfma_f32_16x16x32_bf16(wf[g][kk], h2, acc[g][2], 0, 0, 0);
        acc[g][3] = __builtin_amdgcn_mfma_f32_16x16x32_bf16(wf[g][kk], h3, acc[g][3], 0, 0, 0);
      }
    }
    // partials: C row m = q*4+r, col b = bt*16+l15   (2-way banks: free)
#pragma unroll
    for (int g = 0; g < 3; ++g)
#pragma unroll
      for (int bt = 0; bt < 4; ++bt)
#pragma unroll
        for (int r = 0; r < 4; ++r)
          part[w][g][q * 4 + r][bt * 16 + l15] = acc[g][bt][r];
    __syncthreads();

    // ---- combine: thread owns (b=cb, m in [cmq,cmq+4)) ----
    {
      float4 hv = *(float4*)&hown[cb][cmq];
      u16x4 pk;
#pragma unroll
      for (int r = 0; r < 4; ++r) {
        int m = cmq + r;
        float hr = part[0][0][m][cb] + part[1][0][m][cb] + part[2][0][m][cb] + part[3][0][m][cb] + bh_lds[0][m];
        float hz = part[0][1][m][cb] + part[1][1][m][cb] + part[2][1][m][cb] + part[3][1][m][cb] + bh_lds[1][m];
        float hn = part[0][2][m][cb] + part[1][2][m][cb] + part[2][2][m][cb] + part[3][2][m][cb] + bh_lds[2][m];
        float xr = bf2f(xq[0][r]), xz = bf2f(xq[1][r]), xn = bf2f(xq[2][r]);
        float rr = 1.f / (1.f + __expf(-(xr + hr)));
        float zz = 1.f / (1.f + __expf(-(xz + hz)));
        float ex = __expf(2.f * (xn + rr * hn));
        float nn = 1.f - 2.f / (ex + 1.f);       // tanh
        float hold = (r == 0) ? hv.x : (r == 1) ? hv.y : (r == 2) ? hv.z : hv.w;
        float hnew = (1.f - zz) * nn + zz * hold;
        if (r == 0) hv.x = hnew; else if (r == 1) hv.y = hnew; else if (r == 2) hv.z = hnew; else hv.w = hnew;
        pk[r] = f2bf(hnew);
      }
      *(float4*)&hown[cb][cmq] = hv;
      if (t + 1 < S_LEN) {
        // MALL-direct 8B h store (sc0 sc1): never dirties L2
        __hip_atomic_store((unsigned long long*)(hnxt + (size_t)cb * HDIM + j0 + cmq),
                           __builtin_bit_cast(unsigned long long, pk),
                           __ATOMIC_RELAXED, __HIP_MEMORY_SCOPE_AGENT);
      }
    }
    __syncthreads();   // every wave waits vmcnt(0): ALL h stores at MALL before flag

    if (t + 1 < S_LEN) {
      // arrive
      if (tid == 0)
        __hip_atomic_fetch_add(bar, 1u, __ATOMIC_RELEASE, __HIP_MEMORY_SCOPE_AGENT);
      // prefetch xg for t+1 while waiting (latency hides under the poll)
#pragma unroll
      for (int g = 0; g < 3; ++g)
#pragma unroll
        for (int r = 0; r < 4; ++r)
          xq[g][r] = xg[((size_t)(t + 1) * GDIM + g * HDIM + j0 + cmq + r) * BATCH + cb];
      // wait
      if (tid == 0) {
        unsigned target = 64u * (unsigned)(t + 1);
        unsigned spins = 0;
        while (__hip_atomic_load(bar, __ATOMIC_RELAXED, __HIP_MEMORY_SCOPE_AGENT) < target) {
          __builtin_amdgcn_s_sleep(1);
          if (++spins > 100000000u) break;  // safety: wrong answer beats a hang
        }
      }
      __syncthreads();
    }
  }

  // final h -> out[b][j]  (fp32, float4)
  *(float4*)(out + (size_t)cb * HDIM + j0 + cmq) = *(float4*)&hown[cb][cmq];
}

// ---------------------------------------------------------------------------
extern "C" void kernel_launch(void* const* d_in, const int* in_sizes, int n_in,
                              void* d_out, int out_size, void* d_ws, size_t ws_size,
                              hipStream_t stream) {
  const float* U   = (const float*)d_in[0];
  const float* Wih = (const float*)d_in[1];
  const float* Whh = (const float*)d_in[2];
  const float* bih = (const float*)d_in[3];
  const float* bhh = (const float*)d_in[4];
  float* out = (float*)d_out;

  char* ws = (char*)d_ws;
  const size_t XG_BYTES = (size_t)S_LEN * GDIM * BATCH * 2;  // 201326592
  unsigned short* xg   = (unsigned short*)ws;
  unsigned short* hbuf = (unsigned short*)(ws + XG_BYTES);
  const size_t H_BYTES = (size_t)2 * BATCH * HDIM * 2;       // 262144
  unsigned int* bar    = (unsigned int*)(ws + XG_BYTES + H_BYTES);

  // zero h(0) double-buffer + barrier counter (ws is poisoned 0xAA each call)
  hipMemsetAsync(ws + XG_BYTES, 0, H_BYTES + 64, stream);

  hipLaunchKernelGGL(xg_gemm, dim3((32768 / 128) * (GDIM / 128)), dim3(256), 0, stream,
                     U, Wih, bih, xg);
  hipLaunchKernelGGL(gru_scan, dim3(64), dim3(256), 0, stream,
                     Whh, bhh, xg, hbuf, bar, out);
}

// Round 5
// 4737.114 us; speedup vs baseline: 1.5294x; 1.5294x over previous
//
#include <hip/hip_runtime.h>

// Problem constants (B,S,D,H = 64,512,1024,1024)
#define S_LEN 512
#define BATCH 64
#define HDIM  1024
#define GDIM  3072   // 3*H

typedef __attribute__((ext_vector_type(8))) short bf16x8;           // MFMA A/B frag (8 bf16)
typedef __attribute__((ext_vector_type(4))) float f32x4;            // MFMA C/D frag
typedef __attribute__((ext_vector_type(4))) unsigned short u16x4;   // 4 bf16

__device__ inline unsigned short f2bf(float f) {
  unsigned u = __builtin_bit_cast(unsigned, f);
  u += 0x7fffu + ((u >> 16) & 1u);          // RNE (inputs are normal floats)
  return (unsigned short)(u >> 16);
}
__device__ inline float bf2f(unsigned short h) {
  unsigned u = ((unsigned)h) << 16;
  return __builtin_bit_cast(float, u);
}
__device__ inline bf16x8 pack8(float4 a, float4 b) {
  bf16x8 r;
  r[0] = (short)f2bf(a.x); r[1] = (short)f2bf(a.y);
  r[2] = (short)f2bf(a.z); r[3] = (short)f2bf(a.w);
  r[4] = (short)f2bf(b.x); r[5] = (short)f2bf(b.y);
  r[6] = (short)f2bf(b.z); r[7] = (short)f2bf(b.w);
  return r;
}

// ---------------------------------------------------------------------------
// Phase 1: xg[s][g][b] = sum_d U[b][s][d] * Wih[g][d] + bih[g]   (bf16 out)
// (unchanged this round)
// ---------------------------------------------------------------------------
__global__ __launch_bounds__(256, 2) void xg_gemm(
    const float* __restrict__ U, const float* __restrict__ Wih,
    const float* __restrict__ bih, unsigned short* __restrict__ xg) {
  __shared__ bf16x8 Asub[512];   // 128 rows x 4 chunks (8KB)
  __shared__ bf16x8 Bsub[512];

  const int bid = blockIdx.x;
  const int nt = bid % 24;       // N-tile (gate cols) fastest: W_ih L2 reuse
  const int mt = bid / 24;
  const int tid = threadIdx.x;
  const int wave = tid >> 6, lane = tid & 63;
  const int q = lane >> 4, l15 = lane & 15;
  const int wm = wave >> 1, wn = wave & 1;

  const int srow = tid >> 1, shalf = tid & 1;
  const int arow = mt * 128 + srow;            // M index = s*64+b ordering
  const float* Ag = U + ((size_t)(arow & 63) * S_LEN + (arow >> 6)) * HDIM + shalf * 16;
  const float* Bg = Wih + (size_t)(nt * 128 + srow) * HDIM + shalf * 16;
  const int sw = (srow >> 1) & 3;
  const int slot0 = srow * 4 + ((shalf * 2) ^ sw);
  const int slot1 = srow * 4 + ((shalf * 2 + 1) ^ sw);

  f32x4 acc[4][4];
#pragma unroll
  for (int i = 0; i < 4; ++i)
#pragma unroll
    for (int j = 0; j < 4; ++j) acc[i][j] = (f32x4){0.f, 0.f, 0.f, 0.f};

  for (int kk = 0; kk < 32; ++kk) {
    const float4* ap = (const float4*)(Ag + kk * 32);
    float4 a0 = ap[0], a1 = ap[1], a2 = ap[2], a3 = ap[3];
    const float4* bp = (const float4*)(Bg + kk * 32);
    float4 b0 = bp[0], b1 = bp[1], b2 = bp[2], b3 = bp[3];
    Asub[slot0] = pack8(a0, a1);
    Asub[slot1] = pack8(a2, a3);
    Bsub[slot0] = pack8(b0, b1);
    Bsub[slot1] = pack8(b2, b3);
    __syncthreads();
    bf16x8 af[4], bfr[4];
#pragma unroll
    for (int i = 0; i < 4; ++i) {
      int ar = wm * 64 + i * 16 + l15;
      af[i] = Asub[ar * 4 + (q ^ ((ar >> 1) & 3))];
      int br = wn * 64 + i * 16 + l15;
      bfr[i] = Bsub[br * 4 + (q ^ ((br >> 1) & 3))];
    }
#pragma unroll
    for (int i = 0; i < 4; ++i)
#pragma unroll
      for (int j = 0; j < 4; ++j)
        acc[i][j] = __builtin_amdgcn_mfma_f32_16x16x32_bf16(af[i], bfr[j], acc[i][j], 0, 0, 0);
    __syncthreads();
  }

#pragma unroll
  for (int j = 0; j < 4; ++j) {
    int gcol = nt * 128 + wn * 64 + j * 16 + l15;
    float bias = bih[gcol];
#pragma unroll
    for (int i = 0; i < 4; ++i) {
      int rbase = mt * 128 + wm * 64 + i * 16 + q * 4;
      int s = rbase >> 6;
      int b0i = rbase & 63;
      u16x4 pk;
#pragma unroll
      for (int r = 0; r < 4; ++r) pk[r] = f2bf(acc[i][j][r] + bias);
      *(u16x4*)(xg + ((size_t)s * GDIM + gcol) * BATCH + b0i) = pk;
    }
  }
}

// ---------------------------------------------------------------------------
// Phase 2 (round-5): persistent GRU scan, 64 blocks x 256 threads.
// Block p owns h-cols [16p,16p+16); wave w owns k in [256w,256w+256) and
// computes partial pre-activations for all 3 gates (W_hh frags in VGPRs).
//
// Sync protocol (round-5):
//  * h stores: 8B relaxed agent atomics (write-through to MALL) -> L2 never
//    dirty -> NO wbl2 anywhere.
//  * barrier: FLAG ARRAY, not a contended counter. Block p stores t+1 to its
//    own dword flags[p] (after __syncthreads vmcnt-drains all h stores).
//    Wave 0's 64 lanes spin on flags[lane] (relaxed sc0sc1 loads, one
//    coalesced 256B poll/iter). Round 1-4's single-counter fetch_add
//    serialized 64 cross-XCD RMWs on one hot line every step.
//  * after poll: ONE acquire agent fence (buffer_inv sc1) -> cached h loads
//    are fresh AND get XCD L2 sharing (round 4 proved MALL-direct loads are
//    ~2.4us/step worse than cached+inv: 8 blocks/XCD share first-miss fills).
//  * xg prefetch for t+1 issued between flag store and poll.
// ---------------------------------------------------------------------------
__global__ __launch_bounds__(256, 1) void gru_scan(
    const float* __restrict__ Whh, const float* __restrict__ bhh,
    const unsigned short* __restrict__ xg, unsigned short* __restrict__ hbuf,
    unsigned int* __restrict__ flags, float* __restrict__ out) {
  __shared__ float part[4][3][16][66];       // ~50.7 KB per-wave partial gates
  __shared__ float hown[64][16];             // fp32 carry [b][m]
  __shared__ float bh_lds[3][16];

  const int p = blockIdx.x;
  const int j0 = p * 16;
  const int tid = threadIdx.x;
  const int w = tid >> 6, lane = tid & 63;
  const int q = lane >> 4, l15 = lane & 15;
  const int k0 = w * 256;
  const int cb = tid >> 2;            // combine: batch row 0..63
  const int cmq = (tid & 3) * 4;      // combine: m-quad 0,4,8,12

  // A-frags: wf[g][kk] = Whh[g*1024 + j0 + l15][k0 + kk*32 + q*8 .. +7]
  bf16x8 wf[3][8];
#pragma unroll
  for (int g = 0; g < 3; ++g) {
    const float* wrow = Whh + ((size_t)g * HDIM + j0 + l15) * HDIM + k0;
#pragma unroll
    for (int kk = 0; kk < 8; ++kk) {
      const float4* wp = (const float4*)(wrow + kk * 32 + q * 8);
      wf[g][kk] = pack8(wp[0], wp[1]);
    }
  }
  if (tid < 48) bh_lds[tid >> 4][tid & 15] = bhh[(tid >> 4) * HDIM + j0 + (tid & 15)];
  { float4 z = {0.f, 0.f, 0.f, 0.f}; *(float4*)&hown[cb][cmq] = z; }
  __syncthreads();

  // prefetch xg for t=0
  unsigned short xq[3][4];
#pragma unroll
  for (int g = 0; g < 3; ++g)
#pragma unroll
    for (int r = 0; r < 4; ++r)
      xq[g][r] = xg[((size_t)g * HDIM + j0 + cmq + r) * BATCH + cb];

  for (int t = 0; t < S_LEN; ++t) {
    const unsigned short* hcur = hbuf + (size_t)(t & 1) * (BATCH * HDIM);
    unsigned short* hnxt = hbuf + (size_t)((t + 1) & 1) * (BATCH * HDIM);

    // ---- GEMM phase: hgT partials, cached h loads (L2-shared per XCD) ----
    f32x4 acc[3][4];
#pragma unroll
    for (int g = 0; g < 3; ++g)
#pragma unroll
      for (int bt = 0; bt < 4; ++bt) acc[g][bt] = (f32x4){0.f, 0.f, 0.f, 0.f};

    const unsigned short* hb = hcur + k0 + q * 8;
#pragma unroll
    for (int kk = 0; kk < 8; ++kk) {
      bf16x8 h0 = *(const bf16x8*)(hb + (size_t)(l15) * HDIM + kk * 32);
      bf16x8 h1 = *(const bf16x8*)(hb + (size_t)(16 + l15) * HDIM + kk * 32);
      bf16x8 h2 = *(const bf16x8*)(hb + (size_t)(32 + l15) * HDIM + kk * 32);
      bf16x8 h3 = *(const bf16x8*)(hb + (size_t)(48 + l15) * HDIM + kk * 32);
#pragma unroll
      for (int g = 0; g < 3; ++g) {
        acc[g][0] = __builtin_amdgcn_mfma_f32_16x16x32_bf16(wf[g][kk], h0, acc[g][0], 0, 0, 0);
        acc[g][1] = __builtin_amdgcn_mfma_f32_16x16x32_bf16(wf[g][kk], h1, acc[g][1], 0, 0, 0);
        acc[g][2] = __builtin_amdgcn_mfma_f32_16x16x32_bf16(wf[g][kk], h2, acc[g][2], 0, 0, 0);
        acc[g][3] = __builtin_amdgcn_mfma_f32_16x16x32_bf16(wf[g][kk], h3, acc[g][3], 0, 0, 0);
      }
    }
    // partials: C row m = q*4+r, col b = bt*16+l15   (2-way banks: free)
#pragma unroll
    for (int g = 0; g < 3; ++g)
#pragma unroll
      for (int bt = 0; bt < 4; ++bt)
#pragma unroll
        for (int r = 0; r < 4; ++r)
          part[w][g][q * 4 + r][bt * 16 + l15] = acc[g][bt][r];
    __syncthreads();

    // ---- combine: thread owns (b=cb, m in [cmq,cmq+4)) ----
    {
      float4 hv = *(float4*)&hown[cb][cmq];
      u16x4 pk;
#pragma unroll
      for (int r = 0; r < 4; ++r) {
        int m = cmq + r;
        float hr = part[0][0][m][cb] + part[1][0][m][cb] + part[2][0][m][cb] + part[3][0][m][cb] + bh_lds[0][m];
        float hz = part[0][1][m][cb] + part[1][1][m][cb] + part[2][1][m][cb] + part[3][1][m][cb] + bh_lds[1][m];
        float hn = part[0][2][m][cb] + part[1][2][m][cb] + part[2][2][m][cb] + part[3][2][m][cb] + bh_lds[2][m];
        float xr = bf2f(xq[0][r]), xz = bf2f(xq[1][r]), xn = bf2f(xq[2][r]);
        float rr = 1.f / (1.f + __expf(-(xr + hr)));
        float zz = 1.f / (1.f + __expf(-(xz + hz)));
        float ex = __expf(2.f * (xn + rr * hn));
        float nn = 1.f - 2.f / (ex + 1.f);       // tanh
        float hold = (r == 0) ? hv.x : (r == 1) ? hv.y : (r == 2) ? hv.z : hv.w;
        float hnew = (1.f - zz) * nn + zz * hold;
        if (r == 0) hv.x = hnew; else if (r == 1) hv.y = hnew; else if (r == 2) hv.z = hnew; else hv.w = hnew;
        pk[r] = f2bf(hnew);
      }
      *(float4*)&hown[cb][cmq] = hv;
      if (t + 1 < S_LEN) {
        // write-through 8B h store (sc0 sc1): never dirties L2
        __hip_atomic_store((unsigned long long*)(hnxt + (size_t)cb * HDIM + j0 + cmq),
                           __builtin_bit_cast(unsigned long long, pk),
                           __ATOMIC_RELAXED, __HIP_MEMORY_SCOPE_AGENT);
      }
    }
    __syncthreads();   // every wave drains vmcnt(0): ALL h stores at MALL

    if (t + 1 < S_LEN) {
      // arrive: own flag dword, no RMW, no contention, no wbl2
      if (tid == 0)
        __hip_atomic_store(&flags[p], (unsigned)(t + 1),
                           __ATOMIC_RELAXED, __HIP_MEMORY_SCOPE_AGENT);
      // prefetch xg for t+1 while waiting (latency hides under the poll)
#pragma unroll
      for (int g = 0; g < 3; ++g)
#pragma unroll
        for (int r = 0; r < 4; ++r)
          xq[g][r] = xg[((size_t)(t + 1) * GDIM + g * HDIM + j0 + cmq + r) * BATCH + cb];
      // wait: wave 0, lane i spins on flags[i] (coalesced 256B poll)
      if (tid < 64) {
        unsigned spins = 0;
        while (__hip_atomic_load(&flags[tid], __ATOMIC_RELAXED, __HIP_MEMORY_SCOPE_AGENT)
               < (unsigned)(t + 1)) {
          __builtin_amdgcn_s_sleep(1);
          if (++spins > 50000000u) break;  // safety: wrong answer beats a hang
        }
      }
      __syncthreads();
      // single buffer_inv sc1: fresh h for cached loads (L2-shared per XCD)
      __builtin_amdgcn_fence(__ATOMIC_ACQUIRE, "agent");
    }
  }

  // final h -> out[b][j]  (fp32, float4)
  *(float4*)(out + (size_t)cb * HDIM + j0 + cmq) = *(float4*)&hown[cb][cmq];
}

// ---------------------------------------------------------------------------
extern "C" void kernel_launch(void* const* d_in, const int* in_sizes, int n_in,
                              void* d_out, int out_size, void* d_ws, size_t ws_size,
                              hipStream_t stream) {
  const float* U   = (const float*)d_in[0];
  const float* Wih = (const float*)d_in[1];
  const float* Whh = (const float*)d_in[2];
  const float* bih = (const float*)d_in[3];
  const float* bhh = (const float*)d_in[4];
  float* out = (float*)d_out;

  char* ws = (char*)d_ws;
  const size_t XG_BYTES = (size_t)S_LEN * GDIM * BATCH * 2;  // 201326592
  unsigned short* xg   = (unsigned short*)ws;
  unsigned short* hbuf = (unsigned short*)(ws + XG_BYTES);
  const size_t H_BYTES = (size_t)2 * BATCH * HDIM * 2;       // 262144
  unsigned int* flags  = (unsigned int*)(ws + XG_BYTES + H_BYTES);

  // zero h(0) double-buffer + 64 flag dwords (ws is poisoned 0xAA each call)
  hipMemsetAsync(ws + XG_BYTES, 0, H_BYTES + 256, stream);

  hipLaunchKernelGGL(xg_gemm, dim3((32768 / 128) * (GDIM / 128)), dim3(256), 0, stream,
                     U, Wih, bih, xg);
  hipLaunchKernelGGL(gru_scan, dim3(64), dim3(256), 0, stream,
                     Whh, bhh, xg, hbuf, flags, out);
}